// Round 1
// baseline (691.707 us; speedup 1.0000x reference)
//
#include <hip/hip_runtime.h>
#include <hip/hip_bf16.h>
#include <math.h>

// GPT3 block on MI355X, round 6:
//  - NEW: 256x256 8-phase GEMM (T2 swizzle + T3/T4 counted vmcnt + T5 setprio)
//    used for QKV (z=3, V written transposed), FFA, FFB (split-K=4, atomic).
//  - Z-projection keeps the 128^2 m97-structure kernel (64-block shape is too
//    small for 256^2 tiles).
//  - flash attention unchanged.
// ws fixed 144 MiB: bI bWQ bWK bWV | bQ bK bVT bAV bZ bWZT | bWFFAT bWFFBT
// bFFA aliases [0,33.5MB) (bI..bWV + 1.5MB of bQ — all dead by then).

typedef __bf16 bf16_t;
typedef __bf16 bf16x8 __attribute__((ext_vector_type(8)));
typedef float  f32x4  __attribute__((ext_vector_type(4)));

#define AS1 __attribute__((address_space(1)))
#define AS3 __attribute__((address_space(3)))

__device__ __forceinline__ void load16_lds(const bf16_t* g, bf16_t* l) {
    // 16B per lane, LDS dest = wave-uniform base + lane*16
    __builtin_amdgcn_global_load_lds((AS1 void*)g, (AS3 void*)l, 16, 0, 0);
}

// ---------------- 256x256 8-phase GEMM ----------------
// C = A * B^T over storage: A [M,K] lda, B [N,K] ldb, C [M,N] ldc (bf16 in).
// 512 thr = 8 waves (2M x 4N); per-wave C tile 128x64; BK=64; LDS 128 KiB
// (2 x dbuf x [256][64] for A and B). Staging via global_load_lds (linear
// LDS dest); global source is pre-swizzled: phys chunk pc holds logical
// chunk pc ^ (row&7), and rows are permuted so each 64-row staging
// instruction maps to one (wave-half) consumer group:
//   A: phys = mh*128 + wm*64 + s  <-> logical = wm*128 + mh*64 + s (s<64)
//   B: phys = nh*128 + wn*32 + s  <-> logical = wn*64 + nh*32 + s (s<32)
// Stage order per K-tile: A-h0, B-h0, A-h1, B-h1 (2 instrs each).
// Waits: vmcnt(4) at end of phases 1,2,4 (never 0 in steady state).
// Phase quadrants: (0,0)->(1,0)->(1,1)->(0,1) so af/bv frags are reused
// (12/8/4/8 ds_read_b128 per phase).

__device__ __forceinline__ void stageA256(const bf16_t* __restrict__ Ab, int lda,
                                          int k0, bf16_t* buf, int half,
                                          int w, int lane)
{
    #pragma unroll
    for (int j = 0; j < 2; ++j) {
        const int prw = half * 128 + j * 64 + w * 8;   // wave-uniform phys row
        const int pr  = prw + (lane >> 3);
        const int lr  = ((pr >> 6) & 1) * 128 + (pr >> 7) * 64 + (pr & 63);
        const int lc  = (lane & 7) ^ (pr & 7);
        load16_lds(Ab + (long long)lr * lda + k0 + lc * 8, buf + prw * 64);
    }
}

__device__ __forceinline__ void stageB256(const bf16_t* __restrict__ Bb, int ldb,
                                          int k0, bf16_t* buf, int half,
                                          int w, int lane)
{
    #pragma unroll
    for (int j = 0; j < 2; ++j) {
        const int prw = half * 128 + j * 64 + w * 8;
        const int pr  = prw + (lane >> 3);
        const int lr  = ((pr >> 5) & 3) * 64 + (pr >> 7) * 32 + (pr & 31);
        const int lc  = (lane & 7) ^ (pr & 7);
        load16_lds(Bb + (long long)lr * ldb + k0 + lc * 8, buf + prw * 64);
    }
}

#define G256_PHASE(MH, NH, DOA, DOB, STAGE, WAIT)                              \
  {                                                                            \
    if constexpr (DOA) {                                                       \
      const int arow_ = (MH) * 128 + wm * 64 + (lane & 15);                    \
      _Pragma("unroll")                                                        \
      for (int ks = 0; ks < 2; ++ks) {                                         \
        const int ch_ = (((ks * 4 + (lane >> 4)) ^ (lane & 7)) * 8);           \
        _Pragma("unroll")                                                      \
        for (int mi = 0; mi < 4; ++mi)                                         \
          af[ks][mi] = *(const bf16x8*)&Ac[(arow_ + mi * 16) * 64 + ch_];      \
      }                                                                        \
    }                                                                          \
    if constexpr (DOB) {                                                       \
      const int brow_ = (NH) * 128 + wn * 32 + (lane & 15);                    \
      _Pragma("unroll")                                                        \
      for (int ks = 0; ks < 2; ++ks) {                                         \
        const int ch_ = (((ks * 4 + (lane >> 4)) ^ (lane & 7)) * 8);           \
        _Pragma("unroll")                                                      \
        for (int nj = 0; nj < 2; ++nj)                                         \
          bv[ks][nj] = *(const bf16x8*)&Bc[(brow_ + nj * 16) * 64 + ch_];      \
      }                                                                        \
    }                                                                          \
    STAGE;                                                                     \
    WAIT;                                                                      \
    __builtin_amdgcn_s_barrier();                                              \
    asm volatile("s_waitcnt lgkmcnt(0)" ::: "memory");                         \
    __builtin_amdgcn_s_setprio(1);                                             \
    _Pragma("unroll")                                                          \
    for (int ks = 0; ks < 2; ++ks)                                             \
      _Pragma("unroll")                                                        \
      for (int mi = 0; mi < 4; ++mi)                                           \
        _Pragma("unroll")                                                      \
        for (int nj = 0; nj < 2; ++nj)                                         \
          acc[(MH) * 4 + mi][(NH) * 2 + nj] =                                  \
              __builtin_amdgcn_mfma_f32_16x16x32_bf16(                         \
                  af[ks][mi], bv[ks][nj],                                      \
                  acc[(MH) * 4 + mi][(NH) * 2 + nj], 0, 0, 0);                 \
    __builtin_amdgcn_s_setprio(0);                                             \
    __builtin_amdgcn_s_barrier();                                              \
  }

template<typename TOUT, bool ATOMIC>
__global__ __launch_bounds__(512, 2)
void gemm256_bt(const bf16_t* __restrict__ A, const bf16_t* __restrict__ B,
                TOUT* __restrict__ Cc, int Kdim,
                int lda, int ldb, int ldc,
                long long ab, long long bb, long long cb,
                int ct_z, bf16_t* __restrict__ ctc, int ldct)
{
    __shared__ __attribute__((aligned(16))) bf16_t Asl[2][256 * 64];
    __shared__ __attribute__((aligned(16))) bf16_t Bsl[2][256 * 64];

    const int z = blockIdx.z;
    A  += (long long)z * ab;
    B  += (long long)z * bb;
    Cc += (long long)z * cb;

    const int bm = blockIdx.y * 256;
    const int bn = blockIdx.x * 256;
    const int t = threadIdx.x, lane = t & 63, w = t >> 6;
    const int wm = w >> 2, wn = w & 3;

    const bf16_t* Ab = A + (long long)bm * lda;
    const bf16_t* Bb = B + (long long)bn * ldb;

    f32x4  acc[8][4] = {};
    bf16x8 af[2][4];    // current A-half frags  [ks][mi4]
    bf16x8 bv[2][2];    // current B-quadrant frags [ks][nj2]

    // prologue: stage K-tile 0 into buf0 (order a0,b0,a1,b1 = 8 instrs),
    // wait all but last 4 -> A-h0,B-h0 resident; a1,b1 in flight.
    stageA256(Ab, lda, 0, &Asl[0][0], 0, w, lane);
    stageB256(Bb, ldb, 0, &Bsl[0][0], 0, w, lane);
    stageA256(Ab, lda, 0, &Asl[0][0], 1, w, lane);
    stageB256(Bb, ldb, 0, &Bsl[0][0], 1, w, lane);
    asm volatile("s_waitcnt vmcnt(4)" ::: "memory");
    __builtin_amdgcn_s_barrier();

    const int NT = Kdim >> 6;
    for (int kt = 0; kt < NT - 1; ++kt) {
        const int cur = kt & 1, nxt = cur ^ 1;
        const int k0n = (kt + 1) << 6;
        const bf16_t* Ac = &Asl[cur][0];
        const bf16_t* Bc = &Bsl[cur][0];
        G256_PHASE(0, 0, 1, 1, stageA256(Ab, lda, k0n, &Asl[nxt][0], 0, w, lane),
                   asm volatile("s_waitcnt vmcnt(4)" ::: "memory"));
        G256_PHASE(1, 0, 1, 0, stageB256(Bb, ldb, k0n, &Bsl[nxt][0], 0, w, lane),
                   asm volatile("s_waitcnt vmcnt(4)" ::: "memory"));
        G256_PHASE(1, 1, 0, 1, stageA256(Ab, lda, k0n, &Asl[nxt][0], 1, w, lane),
                   ((void)0));
        G256_PHASE(0, 1, 1, 0, stageB256(Bb, ldb, k0n, &Bsl[nxt][0], 1, w, lane),
                   asm volatile("s_waitcnt vmcnt(4)" ::: "memory"));
    }
    {   // tail K-tile: no staging, drain counted
        const int cur = (NT - 1) & 1;
        const bf16_t* Ac = &Asl[cur][0];
        const bf16_t* Bc = &Bsl[cur][0];
        G256_PHASE(0, 0, 1, 1, ((void)0),
                   asm volatile("s_waitcnt vmcnt(2)" ::: "memory"));
        G256_PHASE(1, 0, 1, 0, ((void)0),
                   asm volatile("s_waitcnt vmcnt(0)" ::: "memory"));
        G256_PHASE(1, 1, 0, 1, ((void)0), ((void)0));
        G256_PHASE(0, 1, 1, 0, ((void)0), ((void)0));
    }

    // ---- epilogue. C/D layout: col = lane&15, row = (lane>>4)*4 + reg ----
    const int rb = (lane >> 4) * 4;
    const int cc = lane & 15;
    if (z == ct_z) {
        // write C^T[n][m] as bf16; 4 consecutive m -> one 8B store
        #pragma unroll
        for (int mi = 0; mi < 8; ++mi) {
            const long long mb = bm + wm * 128 + mi * 16 + rb;
            #pragma unroll
            for (int nj = 0; nj < 4; ++nj) {
                const long long n = bn + wn * 64 + nj * 16 + cc;
                union { bf16_t b[4]; unsigned long long u; } o;
                #pragma unroll
                for (int r = 0; r < 4; ++r) o.b[r] = (bf16_t)acc[mi][nj][r];
                *(unsigned long long*)(ctc + n * ldct + mb) = o.u;
            }
        }
    } else {
        #pragma unroll
        for (int mi = 0; mi < 8; ++mi) {
            #pragma unroll
            for (int r = 0; r < 4; ++r) {
                const long long m = bm + wm * 128 + mi * 16 + rb + r;
                TOUT* crow = Cc + m * ldc + bn + wn * 64 + cc;
                #pragma unroll
                for (int nj = 0; nj < 4; ++nj) {
                    if constexpr (ATOMIC)
                        atomicAdd(&crow[nj * 16], (float)acc[mi][nj][r]);
                    else
                        crow[nj * 16] = (TOUT)acc[mi][nj][r];
                }
            }
        }
    }
}

// ---------------- GEMM (m97 structure, kept for the 64-tile Z-proj) --------
template<typename TOUT, bool ATOMIC>
__global__ __launch_bounds__(256)
void gemm_bt(const bf16_t* __restrict__ A, const bf16_t* __restrict__ B,
             TOUT* __restrict__ Cc, int Mdim, int Ndim, int Kdim,
             int lda, int ldb, int ldc,
             long long ab, long long bb, long long cb,
             int ct_z, bf16_t* __restrict__ ctc, int ldct)
{
    __shared__ bf16_t As[128 * 32];
    __shared__ bf16_t Bs[128 * 32];

    const int z = blockIdx.z;
    A  += (long long)z * ab;
    B  += (long long)z * bb;
    Cc += (long long)z * cb;

    const int bm = blockIdx.y * 128;
    const int bn = blockIdx.x * 128;
    const int t  = threadIdx.x;
    const int lane = t & 63;
    const int w    = t >> 6;

    const int wm = (w & 1) * 64;
    const int wn = (w >> 1) * 64;

    const int sub = lane >> 2;     // row within 16
    const int seg = lane & 3;      // 16B segment within 64B row

    const bf16_t* Ag0 = A + (long long)(bm + w * 32 + sub) * lda + seg * 8;
    const bf16_t* Ag1 = Ag0 + 16LL * lda;
    const bf16_t* Bg0 = B + (long long)(bn + w * 32 + sub) * ldb + seg * 8;
    const bf16_t* Bg1 = Bg0 + 16LL * ldb;

    bf16_t* Al0 = &As[(w * 2 + 0) * 512];
    bf16_t* Al1 = &As[(w * 2 + 1) * 512];
    bf16_t* Bl0 = &Bs[(w * 2 + 0) * 512];
    bf16_t* Bl1 = &Bs[(w * 2 + 1) * 512];

    const int col  = lane & 15;
    const int koff = (lane >> 4) * 8;

    f32x4 acc[4][4] = {};

    for (int k0 = 0; k0 < Kdim; k0 += 32) {
        load16_lds(Ag0 + k0, Al0);
        load16_lds(Ag1 + k0, Al1);
        load16_lds(Bg0 + k0, Bl0);
        load16_lds(Bg1 + k0, Bl1);
        __syncthreads();

        bf16x8 afr[4], bfr[4];
        #pragma unroll
        for (int mi = 0; mi < 4; ++mi)
            afr[mi] = *(const bf16x8*)&As[(wm + mi * 16 + col) * 32 + koff];
        #pragma unroll
        for (int nj = 0; nj < 4; ++nj)
            bfr[nj] = *(const bf16x8*)&Bs[(wn + nj * 16 + col) * 32 + koff];
        #pragma unroll
        for (int mi = 0; mi < 4; ++mi)
            #pragma unroll
            for (int nj = 0; nj < 4; ++nj)
                acc[mi][nj] = __builtin_amdgcn_mfma_f32_16x16x32_bf16(
                    afr[mi], bfr[nj], acc[mi][nj], 0, 0, 0);
        __syncthreads();
    }

    const int rbase = (lane >> 4) * 4;
    if (z == ct_z) {
        #pragma unroll
        for (int mi = 0; mi < 4; ++mi) {
            const long long mb = bm + wm + mi * 16 + rbase;
            #pragma unroll
            for (int nj = 0; nj < 4; ++nj) {
                const long long n = bn + wn + nj * 16 + col;
                union { bf16_t b[4]; unsigned long long u; } o;
                #pragma unroll
                for (int r = 0; r < 4; ++r) o.b[r] = (bf16_t)acc[mi][nj][r];
                *(unsigned long long*)(ctc + n * ldct + mb) = o.u;
            }
        }
    } else {
        #pragma unroll
        for (int mi = 0; mi < 4; ++mi) {
            #pragma unroll
            for (int r = 0; r < 4; ++r) {
                long long m = bm + wm + mi * 16 + rbase + r;
                TOUT* crow = Cc + m * ldc + bn + wn + col;
                #pragma unroll
                for (int nj = 0; nj < 4; ++nj) {
                    if constexpr (ATOMIC)
                        atomicAdd(&crow[nj * 16], (float)acc[mi][nj][r]);
                    else
                        crow[nj * 16] = (TOUT)acc[mi][nj][r];
                }
            }
        }
    }
}

// ---------------- flash attention ----------------
// Grid (M/64, H). Block 256 = 4 waves; wave owns 16 q-rows. KV tile = 64.
__global__ __launch_bounds__(256, 2)
void flash_attn(const bf16_t* __restrict__ Q, const bf16_t* __restrict__ K,
                const bf16_t* __restrict__ VT, bf16_t* __restrict__ O,
                int M, int D)
{
    __shared__ bf16_t Kt[64 * 128];
    __shared__ bf16_t Vt[128 * 64];
    __shared__ bf16_t Pl[4 * 16 * 88];

    const int t = threadIdx.x, lane = t & 63, w = t >> 6;
    const int q4 = lane >> 4;
    const int c  = lane & 15;
    const int bm = blockIdx.x * 64;
    const int hE = blockIdx.y * 128;

    bf16x8 af_q[4];
    {
        const bf16_t* qrow = Q + (long long)(bm + w * 16 + c) * D + hE + q4 * 8;
        #pragma unroll
        for (int ks = 0; ks < 4; ++ks)
            af_q[ks] = *(const bf16x8*)(qrow + ks * 32);
    }

    f32x4 acc_o[8] = {};
    float m_i[4] = {-INFINITY, -INFINITY, -INFINITY, -INFINITY};
    float l_i[4] = {0.f, 0.f, 0.f, 0.f};

    bf16_t* Pw = &Pl[w * 16 * 88];

    for (int p0 = 0; p0 < M; p0 += 64) {
        #pragma unroll
        for (int j = 0; j < 4; ++j) {
            int krow = w * 16 + j * 4;
            load16_lds(K + (long long)(p0 + krow + q4) * D + hE + ((c ^ (j * 4 + q4)) * 8),
                       &Kt[krow * 128]);
            int vrow = w * 32 + j * 8;
            load16_lds(VT + (long long)(hE + vrow + (lane >> 3)) * M + p0
                          + (((lane & 7) ^ (lane >> 3)) * 8),
                       &Vt[vrow * 64]);
        }
        __syncthreads();

        f32x4 acc_s[4] = {};
        #pragma unroll
        for (int ks = 0; ks < 4; ++ks) {
            #pragma unroll
            for (int nj = 0; nj < 4; ++nj) {
                int row = nj * 16 + c;
                bf16x8 bk = *(const bf16x8*)&Kt[row * 128 + (((ks * 4 + q4) ^ c) * 8)];
                acc_s[nj] = __builtin_amdgcn_mfma_f32_16x16x32_bf16(
                    af_q[ks], bk, acc_s[nj], 0, 0, 0);
            }
        }

        float mt[4], alpha[4], rs[4];
        #pragma unroll
        for (int r = 0; r < 4; ++r) {
            float v = fmaxf(fmaxf(acc_s[0][r], acc_s[1][r]),
                            fmaxf(acc_s[2][r], acc_s[3][r]));
            #pragma unroll
            for (int off = 1; off < 16; off <<= 1)
                v = fmaxf(v, __shfl_xor(v, off));
            mt[r] = v;
        }
        #pragma unroll
        for (int r = 0; r < 4; ++r) {
            float mn = fmaxf(m_i[r], mt[r]);
            alpha[r] = __expf(m_i[r] - mn);
            m_i[r] = mn;
            rs[r] = 0.f;
        }
        #pragma unroll
        for (int nj = 0; nj < 4; ++nj)
            #pragma unroll
            for (int r = 0; r < 4; ++r) {
                float p = __expf(acc_s[nj][r] - m_i[r]);
                rs[r] += p;
                Pw[(q4 * 4 + r) * 88 + nj * 16 + c] = (bf16_t)p;
            }
        #pragma unroll
        for (int r = 0; r < 4; ++r) {
            float v = rs[r];
            #pragma unroll
            for (int off = 1; off < 16; off <<= 1)
                v += __shfl_xor(v, off);
            l_i[r] = alpha[r] * l_i[r] + v;
        }
        #pragma unroll
        for (int nj = 0; nj < 8; ++nj)
            #pragma unroll
            for (int r = 0; r < 4; ++r)
                acc_o[nj][r] *= alpha[r];
        __syncthreads();

        #pragma unroll
        for (int ks = 0; ks < 2; ++ks) {
            bf16x8 ap = *(const bf16x8*)&Pw[c * 88 + ks * 32 + q4 * 8];
            #pragma unroll
            for (int nj = 0; nj < 8; ++nj) {
                int row = nj * 16 + c;
                bf16x8 bvv = *(const bf16x8*)&Vt[row * 64 + (((ks * 4 + q4) ^ (c & 7)) * 8)];
                acc_o[nj] = __builtin_amdgcn_mfma_f32_16x16x32_bf16(
                    ap, bvv, acc_o[nj], 0, 0, 0);
            }
        }
        __syncthreads();
    }

    float inv[4];
    #pragma unroll
    for (int r = 0; r < 4; ++r) inv[r] = 1.0f / l_i[r];
    #pragma unroll
    for (int nj = 0; nj < 8; ++nj)
        #pragma unroll
        for (int r = 0; r < 4; ++r)
            O[(long long)(bm + w * 16 + q4 * 4 + r) * D + hE + nj * 16 + c] =
                (bf16_t)(acc_o[nj][r] * inv[r]);
}

// ---------------- small utility kernels ----------------
__global__ __launch_bounds__(256)
void cast4_bf16(const float* __restrict__ s0, const float* __restrict__ s1,
                const float* __restrict__ s2, const float* __restrict__ s3,
                bf16_t* __restrict__ d0, long long seg, long long n)
{
    const float* src = (blockIdx.y == 0) ? s0 : (blockIdx.y == 1) ? s1
                     : (blockIdx.y == 2) ? s2 : s3;
    bf16_t* dst = d0 + (long long)blockIdx.y * seg;
    long long i = ((long long)blockIdx.x * 256 + threadIdx.x) * 4;
    if (i >= n) return;
    float4 v = *(const float4*)(src + i);
    union { bf16_t b[4]; unsigned long long u; } o;
    o.b[0] = (bf16_t)v.x; o.b[1] = (bf16_t)v.y;
    o.b[2] = (bf16_t)v.z; o.b[3] = (bf16_t)v.w;
    *(unsigned long long*)(dst + i) = o.u;
}

__global__ __launch_bounds__(256)
void transpose_to_bf16(const float* __restrict__ in, bf16_t* __restrict__ out,
                       int rows, int cols)
{
    __shared__ bf16_t tile[32][33];
    const int r0 = blockIdx.y * 32, c0 = blockIdx.x * 32;
    const int tx = threadIdx.x & 31, ty = threadIdx.x >> 5;
    #pragma unroll
    for (int i = 0; i < 4; ++i) {
        int r = ty + i * 8;
        tile[r][tx] = (bf16_t)in[(long long)(r0 + r) * cols + c0 + tx];
    }
    __syncthreads();
    #pragma unroll
    for (int i = 0; i < 4; ++i) {
        int r = ty + i * 8;
        out[(long long)(c0 + r) * rows + r0 + tx] = tile[tx][r];
    }
}

__global__ __launch_bounds__(256)
void zero_f32(float* __restrict__ p, long long n)
{
    long long i = ((long long)blockIdx.x * 256 + threadIdx.x) * 4;
    if (i >= n) return;
    *(float4*)(p + i) = float4{0.f, 0.f, 0.f, 0.f};
}

extern "C" void kernel_launch(void* const* d_in, const int* in_sizes, int n_in,
                              void* d_out, int out_size, void* d_ws, size_t ws_size,
                              hipStream_t stream)
{
    const float* I    = (const float*)d_in[0];
    const float* WV   = (const float*)d_in[1];
    const float* WK   = (const float*)d_in[2];
    const float* WQ   = (const float*)d_in[3];
    const float* WZ   = (const float*)d_in[4];
    const float* WFFA = (const float*)d_in[5];
    const float* WFFB = (const float*)d_in[6];
    float* out = (float*)d_out;                  // [M, D] fp32

    const int M = 2048, D = 2048, C = 8192;
    const long long MD = (long long)M * D;
    const size_t MiB = 1024 * 1024;

    char* base = (char*)d_ws;
    bf16_t* bI     = (bf16_t*)(base + 0 * MiB);
    bf16_t* bWQ    = (bf16_t*)(base + 8 * MiB);    // contiguous WQ,WK,WV (z-batch)
    bf16_t* bWK    = (bf16_t*)(base + 16 * MiB);
    bf16_t* bWV    = (bf16_t*)(base + 24 * MiB);
    bf16_t* bQ     = (bf16_t*)(base + 32 * MiB);   // contiguous Q,K (z-batch out)
    bf16_t* bK     = (bf16_t*)(base + 40 * MiB);
    bf16_t* bVT    = (bf16_t*)(base + 48 * MiB);   // [D, M] via ct_z epilogue
    bf16_t* bAV    = (bf16_t*)(base + 56 * MiB);
    bf16_t* bZ     = (bf16_t*)(base + 64 * MiB);
    bf16_t* bWZT   = (bf16_t*)(base + 72 * MiB);
    bf16_t* bWFFAT = (bf16_t*)(base + 80 * MiB);   // [C, D]
    bf16_t* bWFFBT = (bf16_t*)(base + 112 * MiB);  // [D, C]
    bf16_t* bFFA   = (bf16_t*)(base + 0 * MiB);    // [M, C] bf16 (bI..bQ-head dead)

    const dim3 blk(256);
    const dim3 blk512(512);

    // ---- prep: casts + weight transposes ----
    cast4_bf16<<<dim3(MD / 1024, 4), blk, 0, stream>>>(I, WQ, WK, WV, bI, MD, MD);
    transpose_to_bf16<<<dim3(D / 32, D / 32), blk, 0, stream>>>(WZ,   bWZT,   D, D);
    transpose_to_bf16<<<dim3(C / 32, D / 32), blk, 0, stream>>>(WFFA, bWFFAT, D, C);
    transpose_to_bf16<<<dim3(D / 32, C / 32), blk, 0, stream>>>(WFFB, bWFFBT, C, D);

    // ---- QKV in one z=3 dispatch (256^2 tiles, 192 blocks); V -> bVT ----
    gemm256_bt<bf16_t, false><<<dim3(8, 8, 3), blk512, 0, stream>>>(
        bI, bWQ, bQ, D, D, D, D, 0, MD, MD, /*ct_z=*/2, bVT, M);

    // ---- flash attention: Q,K,VT -> AV ----
    flash_attn<<<dim3(M / 64, 16), blk, 0, stream>>>(bQ, bK, bVT, bAV, M, D);

    // ---- Z = AV x WZ^T (64 tiles at 256^2 -> keep 128^2 kernel) ----
    gemm_bt<bf16_t, false><<<dim3(16, 16, 1), blk, 0, stream>>>(
        bAV, bWZT, bZ, M, D, D, D, D, D, 0, 0, 0, -1, nullptr, 0);

    // ---- FFA = Z x WFFA^T  (256 blocks, the 8-phase sweet spot) ----
    gemm256_bt<bf16_t, false><<<dim3(32, 8, 1), blk512, 0, stream>>>(
        bZ, bWFFAT, bFFA, D, D, D, C, 0, 0, 0, -1, nullptr, 0);

    // ---- FFB = FFA x WFFB^T, split-K=4 with atomic f32 accumulate ----
    zero_f32<<<dim3((int)(MD / 1024)), blk, 0, stream>>>(out, MD);
    gemm256_bt<float, true><<<dim3(8, 8, 4), blk512, 0, stream>>>(
        bFFA, bWFFBT, out, 2048, C, C, D, 2048, 2048, 0, -1, nullptr, 0);
}

// Round 2
// 631.159 us; speedup vs baseline: 1.0959x; 1.0959x over previous
//
#include <hip/hip_runtime.h>
#include <hip/hip_bf16.h>
#include <math.h>

// GPT3 block on MI355X, round 7:
//  - NEW gemm256d_bt: 256x256 tile, 4-deep HALF-TILE RING pipeline.
//    Each 16KB half staged ~6 phases before use (vmcnt 10/10/8, 3 barriers
//    per K-tile, 24 ds_read_b128/K-tile/wave = minimal). Fixes the round-6
//    Little's-law stall (2-phase cover -> 1.5 TB/s ceiling, MfmaUtil 18%).
//  - FFB: split-K=4 to 4 fp32 partial buffers (plain stores, no atomics)
//    + fused reduce4 into d_out. zero_f32 dropped.
//  - Z-projection keeps the 128^2 m97-structure kernel; attention unchanged.
// ws 144 MiB: bI bWQ bWK bWV | bQ bK bVT bAV bZ bWZT | bWFFAT bWFFBT
// bFFA aliases [0,32MiB). FFB partials alias [32,96MiB) (all dead there).

typedef __bf16 bf16_t;
typedef __bf16 bf16x8 __attribute__((ext_vector_type(8)));
typedef float  f32x4  __attribute__((ext_vector_type(4)));

#define AS1 __attribute__((address_space(1)))
#define AS3 __attribute__((address_space(3)))

__device__ __forceinline__ void load16_lds(const bf16_t* g, bf16_t* l) {
    // 16B per lane, LDS dest = wave-uniform base + lane*16
    __builtin_amdgcn_global_load_lds((AS1 void*)g, (AS3 void*)l, 16, 0, 0);
}

// ---- half-tile staging (ring slot = 128 rows x 64 cols, 16KB) ----
// A half h = logical rows {r : (r>>6)&1 == h} (bit6 partition)
// B half h = logical rows {r : (r>>5)&1 == h} (bit5 partition)
// chunk c of phys row p holds logical chunk c ^ (p&7)  (read-side XOR swizzle)
__device__ __forceinline__ void stageA_half(const bf16_t* __restrict__ Ab, int lda,
                                            int k0, int h, bf16_t* slot,
                                            int w, int lane)
{
    #pragma unroll
    for (int j = 0; j < 2; ++j) {
        const int prw = j * 64 + w * 8;          // wave-uniform phys row base
        const int p   = prw + (lane >> 3);
        const int lr  = (p >> 6) * 128 + h * 64 + (p & 63);
        const int lc  = (lane & 7) ^ (p & 7);
        load16_lds(Ab + (long long)lr * lda + k0 + lc * 8, slot + prw * 64);
    }
}
__device__ __forceinline__ void stageB_half(const bf16_t* __restrict__ Bb, int ldb,
                                            int k0, int h, bf16_t* slot,
                                            int w, int lane)
{
    #pragma unroll
    for (int j = 0; j < 2; ++j) {
        const int prw = j * 64 + w * 8;
        const int p   = prw + (lane >> 3);
        const int lr  = (p >> 5) * 64 + h * 32 + (p & 31);
        const int lc  = (lane & 7) ^ (p & 7);
        load16_lds(Bb + (long long)lr * ldb + k0 + lc * 8, slot + prw * 64);
    }
}

#define LOADAF(SL)                                                             \
  _Pragma("unroll") for (int ks = 0; ks < 2; ++ks)                             \
  _Pragma("unroll") for (int mi = 0; mi < 4; ++mi)                             \
      af[ks][mi] = *(const bf16x8*)&(SL)[(wm * 64 + mi * 16 + c15) * 64 +      \
                      (((ks * 4 + q4) ^ (c15 & 7)) * 8)];

#define LOADBV(DST, SL)                                                        \
  _Pragma("unroll") for (int ks = 0; ks < 2; ++ks)                             \
  _Pragma("unroll") for (int nj = 0; nj < 2; ++nj)                             \
      DST[ks][nj] = *(const bf16x8*)&(SL)[(wn * 32 + nj * 16 + c15) * 64 +     \
                      (((ks * 4 + q4) ^ (c15 & 7)) * 8)];

#define MFMA16(MH, NH, BV)                                                     \
  __builtin_amdgcn_s_setprio(1);                                               \
  _Pragma("unroll") for (int ks = 0; ks < 2; ++ks)                             \
  _Pragma("unroll") for (int mi = 0; mi < 4; ++mi)                             \
  _Pragma("unroll") for (int nj = 0; nj < 2; ++nj)                             \
      acc[(MH) * 4 + mi][(NH) * 2 + nj] =                                      \
          __builtin_amdgcn_mfma_f32_16x16x32_bf16(                             \
              af[ks][mi], BV[ks][nj], acc[(MH) * 4 + mi][(NH) * 2 + nj],       \
              0, 0, 0);                                                        \
  __builtin_amdgcn_s_setprio(0);

#define VMW(N) asm volatile("s_waitcnt vmcnt(" #N ")" ::: "memory")
#define BAR()  __builtin_amdgcn_s_barrier()

// ---------------- 256x256 deep-ring GEMM ----------------
// C = A * B^T: A [M,K] lda, B [N,K] ldb, C [M,N] ldc. 512 thr = 8 waves
// (2M x 4N), per-wave C 128x64, BK=64 split in A/B halves. Requires NT>=3.
template<typename TOUT>
__global__ __launch_bounds__(512, 2)
void gemm256d_bt(const bf16_t* __restrict__ A, const bf16_t* __restrict__ B,
                 TOUT* __restrict__ Cc, int Kdim,
                 int lda, int ldb, int ldc,
                 long long ab, long long bb, long long cb,
                 int ct_z, bf16_t* __restrict__ ctc, int ldct)
{
    __shared__ __attribute__((aligned(16))) bf16_t As[4][128 * 64];
    __shared__ __attribute__((aligned(16))) bf16_t Bs[4][128 * 64];

    const int z = blockIdx.z;
    A  += (long long)z * ab;
    B  += (long long)z * bb;
    Cc += (long long)z * cb;

    const int bm = blockIdx.y * 256;
    const int bn = blockIdx.x * 256;
    const int t = threadIdx.x, lane = t & 63, w = t >> 6;
    const int wm = w >> 2, wn = w & 3;
    const int q4 = lane >> 4, c15 = lane & 15;

    const bf16_t* Ab = A + (long long)bm * lda;
    const bf16_t* Bb = B + (long long)bn * ldb;

    f32x4  acc[8][4] = {};
    bf16x8 af[2][4];        // current A-half frags
    bf16x8 bv0[2][2];       // B-half0 frags (live p0..p3)
    bf16x8 bv1[2][2];       // B-half1 frags (live p1..p2)

    // ---- prologue: stage tiles 0,1 in steady-state queue order ----
    // queue: [A0(0) B0(0) B1(0) A1(0) A0(1) B0(1) B1(1)]  (14 loads)
    stageA_half(Ab, lda, 0,  0, As[0], w, lane);
    stageB_half(Bb, ldb, 0,  0, Bs[0], w, lane);
    stageB_half(Bb, ldb, 0,  1, Bs[1], w, lane);
    stageA_half(Ab, lda, 0,  1, As[1], w, lane);
    stageA_half(Ab, lda, 64, 0, As[2], w, lane);
    stageB_half(Bb, ldb, 64, 0, Bs[2], w, lane);
    stageB_half(Bb, ldb, 64, 1, Bs[3], w, lane);

    const int NT = Kdim >> 6;

    for (int kt = 0; kt + 2 < NT; ++kt) {
        const int par = kt & 1;
        bf16_t* a0 = As[2 * par];
        bf16_t* a1 = As[2 * par + 1];
        bf16_t* b0 = Bs[2 * par];
        bf16_t* b1 = Bs[2 * par + 1];
        bf16_t* a1n = As[2 * (par ^ 1) + 1];
        const int kn1 = (kt + 1) << 6, kn2 = (kt + 2) << 6;
        // p0: quadrant (A0,B0); stage A1(kt+1)
        VMW(10); BAR();
        stageA_half(Ab, lda, kn1, 1, a1n, w, lane);
        LOADAF(a0); LOADBV(bv0, b0);
        MFMA16(0, 0, bv0);
        // p1: quadrant (A0,B1)
        VMW(10); BAR();
        LOADBV(bv1, b1);
        MFMA16(0, 1, bv1);
        // p2: quadrant (A1,B1); stage A0(kt+2), B0(kt+2)
        VMW(8); BAR();
        stageA_half(Ab, lda, kn2, 0, a0, w, lane);
        stageB_half(Bb, ldb, kn2, 0, b0, w, lane);
        LOADAF(a1);
        MFMA16(1, 1, bv1);
        // p3: quadrant (A1,B0) from regs; stage B1(kt+2); no barrier
        stageB_half(Bb, ldb, kn2, 1, b1, w, lane);
        MFMA16(1, 0, bv0);
    }
    {   // kt = NT-2: stage only A1(NT-1)
        const int kt = NT - 2, par = kt & 1;
        bf16_t* a0 = As[2 * par];
        bf16_t* a1 = As[2 * par + 1];
        bf16_t* b0 = Bs[2 * par];
        bf16_t* b1 = Bs[2 * par + 1];
        bf16_t* a1n = As[2 * (par ^ 1) + 1];
        const int kn1 = (kt + 1) << 6;
        VMW(10); BAR();
        stageA_half(Ab, lda, kn1, 1, a1n, w, lane);
        LOADAF(a0); LOADBV(bv0, b0);
        MFMA16(0, 0, bv0);
        VMW(10); BAR();
        LOADBV(bv1, b1);
        MFMA16(0, 1, bv1);
        VMW(8); BAR();
        LOADAF(a1);
        MFMA16(1, 1, bv1);
        MFMA16(1, 0, bv0);
    }
    {   // kt = NT-1: drain
        const int par = (NT - 1) & 1;
        bf16_t* a0 = As[2 * par];
        bf16_t* a1 = As[2 * par + 1];
        bf16_t* b0 = Bs[2 * par];
        bf16_t* b1 = Bs[2 * par + 1];
        VMW(4); BAR();
        LOADAF(a0); LOADBV(bv0, b0);
        MFMA16(0, 0, bv0);
        VMW(2); BAR();
        LOADBV(bv1, b1);
        MFMA16(0, 1, bv1);
        VMW(0); BAR();
        LOADAF(a1);
        MFMA16(1, 1, bv1);
        MFMA16(1, 0, bv0);
    }

    // ---- epilogue. C/D layout: col = lane&15, row = (lane>>4)*4 + reg ----
    const int rb = q4 * 4;
    if (z == ct_z) {
        // write C^T[n][m] as bf16; 4 consecutive m -> one 8B store
        #pragma unroll
        for (int mi = 0; mi < 8; ++mi) {
            const long long mb = bm + wm * 128 + mi * 16 + rb;
            #pragma unroll
            for (int nj = 0; nj < 4; ++nj) {
                const long long n = bn + wn * 64 + nj * 16 + c15;
                union { bf16_t b[4]; unsigned long long u; } o;
                #pragma unroll
                for (int r = 0; r < 4; ++r) o.b[r] = (bf16_t)acc[mi][nj][r];
                *(unsigned long long*)(ctc + n * ldct + mb) = o.u;
            }
        }
    } else {
        #pragma unroll
        for (int mi = 0; mi < 8; ++mi) {
            #pragma unroll
            for (int r = 0; r < 4; ++r) {
                const long long m = bm + wm * 128 + mi * 16 + rb + r;
                TOUT* crow = Cc + m * ldc + bn + wn * 64 + c15;
                #pragma unroll
                for (int nj = 0; nj < 4; ++nj)
                    crow[nj * 16] = (TOUT)acc[mi][nj][r];
            }
        }
    }
}

// ---------------- GEMM (m97 structure, kept for the 64-tile Z-proj) --------
template<typename TOUT, bool ATOMIC>
__global__ __launch_bounds__(256)
void gemm_bt(const bf16_t* __restrict__ A, const bf16_t* __restrict__ B,
             TOUT* __restrict__ Cc, int Mdim, int Ndim, int Kdim,
             int lda, int ldb, int ldc,
             long long ab, long long bb, long long cb,
             int ct_z, bf16_t* __restrict__ ctc, int ldct)
{
    __shared__ bf16_t Ash[128 * 32];
    __shared__ bf16_t Bsh[128 * 32];

    const int z = blockIdx.z;
    A  += (long long)z * ab;
    B  += (long long)z * bb;
    Cc += (long long)z * cb;

    const int bm = blockIdx.y * 128;
    const int bn = blockIdx.x * 128;
    const int t  = threadIdx.x;
    const int lane = t & 63;
    const int w    = t >> 6;

    const int wm = (w & 1) * 64;
    const int wn = (w >> 1) * 64;

    const int sub = lane >> 2;
    const int seg = lane & 3;

    const bf16_t* Ag0 = A + (long long)(bm + w * 32 + sub) * lda + seg * 8;
    const bf16_t* Ag1 = Ag0 + 16LL * lda;
    const bf16_t* Bg0 = B + (long long)(bn + w * 32 + sub) * ldb + seg * 8;
    const bf16_t* Bg1 = Bg0 + 16LL * ldb;

    bf16_t* Al0 = &Ash[(w * 2 + 0) * 512];
    bf16_t* Al1 = &Ash[(w * 2 + 1) * 512];
    bf16_t* Bl0 = &Bsh[(w * 2 + 0) * 512];
    bf16_t* Bl1 = &Bsh[(w * 2 + 1) * 512];

    const int col  = lane & 15;
    const int koff = (lane >> 4) * 8;

    f32x4 acc[4][4] = {};

    for (int k0 = 0; k0 < Kdim; k0 += 32) {
        load16_lds(Ag0 + k0, Al0);
        load16_lds(Ag1 + k0, Al1);
        load16_lds(Bg0 + k0, Bl0);
        load16_lds(Bg1 + k0, Bl1);
        __syncthreads();

        bf16x8 afr[4], bfr[4];
        #pragma unroll
        for (int mi = 0; mi < 4; ++mi)
            afr[mi] = *(const bf16x8*)&Ash[(wm + mi * 16 + col) * 32 + koff];
        #pragma unroll
        for (int nj = 0; nj < 4; ++nj)
            bfr[nj] = *(const bf16x8*)&Bsh[(wn + nj * 16 + col) * 32 + koff];
        #pragma unroll
        for (int mi = 0; mi < 4; ++mi)
            #pragma unroll
            for (int nj = 0; nj < 4; ++nj)
                acc[mi][nj] = __builtin_amdgcn_mfma_f32_16x16x32_bf16(
                    afr[mi], bfr[nj], acc[mi][nj], 0, 0, 0);
        __syncthreads();
    }

    const int rbase = (lane >> 4) * 4;
    if (z == ct_z) {
        #pragma unroll
        for (int mi = 0; mi < 4; ++mi) {
            const long long mb = bm + wm + mi * 16 + rbase;
            #pragma unroll
            for (int nj = 0; nj < 4; ++nj) {
                const long long n = bn + wn + nj * 16 + col;
                union { bf16_t b[4]; unsigned long long u; } o;
                #pragma unroll
                for (int r = 0; r < 4; ++r) o.b[r] = (bf16_t)acc[mi][nj][r];
                *(unsigned long long*)(ctc + n * ldct + mb) = o.u;
            }
        }
    } else {
        #pragma unroll
        for (int mi = 0; mi < 4; ++mi) {
            #pragma unroll
            for (int r = 0; r < 4; ++r) {
                long long m = bm + wm + mi * 16 + rbase + r;
                TOUT* crow = Cc + m * ldc + bn + wn + col;
                #pragma unroll
                for (int nj = 0; nj < 4; ++nj) {
                    if constexpr (ATOMIC)
                        atomicAdd(&crow[nj * 16], (float)acc[mi][nj][r]);
                    else
                        crow[nj * 16] = (TOUT)acc[mi][nj][r];
                }
            }
        }
    }
}

// ---------------- flash attention ----------------
// Grid (M/64, H). Block 256 = 4 waves; wave owns 16 q-rows. KV tile = 64.
__global__ __launch_bounds__(256, 2)
void flash_attn(const bf16_t* __restrict__ Q, const bf16_t* __restrict__ K,
                const bf16_t* __restrict__ VT, bf16_t* __restrict__ O,
                int M, int D)
{
    __shared__ bf16_t Kt[64 * 128];
    __shared__ bf16_t Vt[128 * 64];
    __shared__ bf16_t Pl[4 * 16 * 88];

    const int t = threadIdx.x, lane = t & 63, w = t >> 6;
    const int q4 = lane >> 4;
    const int c  = lane & 15;
    const int bm = blockIdx.x * 64;
    const int hE = blockIdx.y * 128;

    bf16x8 af_q[4];
    {
        const bf16_t* qrow = Q + (long long)(bm + w * 16 + c) * D + hE + q4 * 8;
        #pragma unroll
        for (int ks = 0; ks < 4; ++ks)
            af_q[ks] = *(const bf16x8*)(qrow + ks * 32);
    }

    f32x4 acc_o[8] = {};
    float m_i[4] = {-INFINITY, -INFINITY, -INFINITY, -INFINITY};
    float l_i[4] = {0.f, 0.f, 0.f, 0.f};

    bf16_t* Pw = &Pl[w * 16 * 88];

    for (int p0 = 0; p0 < M; p0 += 64) {
        #pragma unroll
        for (int j = 0; j < 4; ++j) {
            int krow = w * 16 + j * 4;
            load16_lds(K + (long long)(p0 + krow + q4) * D + hE + ((c ^ (j * 4 + q4)) * 8),
                       &Kt[krow * 128]);
            int vrow = w * 32 + j * 8;
            load16_lds(VT + (long long)(hE + vrow + (lane >> 3)) * M + p0
                          + (((lane & 7) ^ (lane >> 3)) * 8),
                       &Vt[vrow * 64]);
        }
        __syncthreads();

        f32x4 acc_s[4] = {};
        #pragma unroll
        for (int ks = 0; ks < 4; ++ks) {
            #pragma unroll
            for (int nj = 0; nj < 4; ++nj) {
                int row = nj * 16 + c;
                bf16x8 bk = *(const bf16x8*)&Kt[row * 128 + (((ks * 4 + q4) ^ c) * 8)];
                acc_s[nj] = __builtin_amdgcn_mfma_f32_16x16x32_bf16(
                    af_q[ks], bk, acc_s[nj], 0, 0, 0);
            }
        }

        float mt[4], alpha[4], rs[4];
        #pragma unroll
        for (int r = 0; r < 4; ++r) {
            float v = fmaxf(fmaxf(acc_s[0][r], acc_s[1][r]),
                            fmaxf(acc_s[2][r], acc_s[3][r]));
            #pragma unroll
            for (int off = 1; off < 16; off <<= 1)
                v = fmaxf(v, __shfl_xor(v, off));
            mt[r] = v;
        }
        #pragma unroll
        for (int r = 0; r < 4; ++r) {
            float mn = fmaxf(m_i[r], mt[r]);
            alpha[r] = __expf(m_i[r] - mn);
            m_i[r] = mn;
            rs[r] = 0.f;
        }
        #pragma unroll
        for (int nj = 0; nj < 4; ++nj)
            #pragma unroll
            for (int r = 0; r < 4; ++r) {
                float p = __expf(acc_s[nj][r] - m_i[r]);
                rs[r] += p;
                Pw[(q4 * 4 + r) * 88 + nj * 16 + c] = (bf16_t)p;
            }
        #pragma unroll
        for (int r = 0; r < 4; ++r) {
            float v = rs[r];
            #pragma unroll
            for (int off = 1; off < 16; off <<= 1)
                v += __shfl_xor(v, off);
            l_i[r] = alpha[r] * l_i[r] + v;
        }
        #pragma unroll
        for (int nj = 0; nj < 8; ++nj)
            #pragma unroll
            for (int r = 0; r < 4; ++r)
                acc_o[nj][r] *= alpha[r];
        __syncthreads();

        #pragma unroll
        for (int ks = 0; ks < 2; ++ks) {
            bf16x8 ap = *(const bf16x8*)&Pw[c * 88 + ks * 32 + q4 * 8];
            #pragma unroll
            for (int nj = 0; nj < 8; ++nj) {
                int row = nj * 16 + c;
                bf16x8 bvv = *(const bf16x8*)&Vt[row * 64 + (((ks * 4 + q4) ^ (c & 7)) * 8)];
                acc_o[nj] = __builtin_amdgcn_mfma_f32_16x16x32_bf16(
                    ap, bvv, acc_o[nj], 0, 0, 0);
            }
        }
        __syncthreads();
    }

    float inv[4];
    #pragma unroll
    for (int r = 0; r < 4; ++r) inv[r] = 1.0f / l_i[r];
    #pragma unroll
    for (int nj = 0; nj < 8; ++nj)
        #pragma unroll
        for (int r = 0; r < 4; ++r)
            O[(long long)(bm + w * 16 + q4 * 4 + r) * D + hE + nj * 16 + c] =
                (bf16_t)(acc_o[nj][r] * inv[r]);
}

// ---------------- small utility kernels ----------------
__global__ __launch_bounds__(256)
void cast4_bf16(const float* __restrict__ s0, const float* __restrict__ s1,
                const float* __restrict__ s2, const float* __restrict__ s3,
                bf16_t* __restrict__ d0, long long seg, long long n)
{
    const float* src = (blockIdx.y == 0) ? s0 : (blockIdx.y == 1) ? s1
                     : (blockIdx.y == 2) ? s2 : s3;
    bf16_t* dst = d0 + (long long)blockIdx.y * seg;
    long long i = ((long long)blockIdx.x * 256 + threadIdx.x) * 4;
    if (i >= n) return;
    float4 v = *(const float4*)(src + i);
    union { bf16_t b[4]; unsigned long long u; } o;
    o.b[0] = (bf16_t)v.x; o.b[1] = (bf16_t)v.y;
    o.b[2] = (bf16_t)v.z; o.b[3] = (bf16_t)v.w;
    *(unsigned long long*)(dst + i) = o.u;
}

__global__ __launch_bounds__(256)
void transpose_to_bf16(const float* __restrict__ in, bf16_t* __restrict__ out,
                       int rows, int cols)
{
    __shared__ bf16_t tile[32][33];
    const int r0 = blockIdx.y * 32, c0 = blockIdx.x * 32;
    const int tx = threadIdx.x & 31, ty = threadIdx.x >> 5;
    #pragma unroll
    for (int i = 0; i < 4; ++i) {
        int r = ty + i * 8;
        tile[r][tx] = (bf16_t)in[(long long)(r0 + r) * cols + c0 + tx];
    }
    __syncthreads();
    #pragma unroll
    for (int i = 0; i < 4; ++i) {
        int r = ty + i * 8;
        out[(long long)(c0 + r) * rows + r0 + tx] = tile[tx][r];
    }
}

__global__ __launch_bounds__(256)
void reduce4_f32(const float* __restrict__ p, float* __restrict__ out,
                 long long n)
{
    long long i = ((long long)blockIdx.x * 256 + threadIdx.x) * 4;
    if (i >= n) return;
    float4 a = *(const float4*)(p + i);
    float4 b = *(const float4*)(p + n + i);
    float4 c = *(const float4*)(p + 2 * n + i);
    float4 d = *(const float4*)(p + 3 * n + i);
    float4 o;
    o.x = a.x + b.x + c.x + d.x;
    o.y = a.y + b.y + c.y + d.y;
    o.z = a.z + b.z + c.z + d.z;
    o.w = a.w + b.w + c.w + d.w;
    *(float4*)(out + i) = o;
}

extern "C" void kernel_launch(void* const* d_in, const int* in_sizes, int n_in,
                              void* d_out, int out_size, void* d_ws, size_t ws_size,
                              hipStream_t stream)
{
    const float* I    = (const float*)d_in[0];
    const float* WV   = (const float*)d_in[1];
    const float* WK   = (const float*)d_in[2];
    const float* WQ   = (const float*)d_in[3];
    const float* WZ   = (const float*)d_in[4];
    const float* WFFA = (const float*)d_in[5];
    const float* WFFB = (const float*)d_in[6];
    float* out = (float*)d_out;                  // [M, D] fp32

    const int M = 2048, D = 2048, C = 8192;
    const long long MD = (long long)M * D;
    const size_t MiB = 1024 * 1024;

    char* base = (char*)d_ws;
    bf16_t* bI     = (bf16_t*)(base + 0 * MiB);
    bf16_t* bWQ    = (bf16_t*)(base + 8 * MiB);    // contiguous WQ,WK,WV (z-batch)
    bf16_t* bWK    = (bf16_t*)(base + 16 * MiB);
    bf16_t* bWV    = (bf16_t*)(base + 24 * MiB);
    bf16_t* bQ     = (bf16_t*)(base + 32 * MiB);   // contiguous Q,K (z-batch out)
    bf16_t* bK     = (bf16_t*)(base + 40 * MiB);
    bf16_t* bVT    = (bf16_t*)(base + 48 * MiB);   // [D, M] via ct_z epilogue
    bf16_t* bAV    = (bf16_t*)(base + 56 * MiB);
    bf16_t* bZ     = (bf16_t*)(base + 64 * MiB);
    bf16_t* bWZT   = (bf16_t*)(base + 72 * MiB);
    bf16_t* bWFFAT = (bf16_t*)(base + 80 * MiB);   // [C, D]
    bf16_t* bWFFBT = (bf16_t*)(base + 112 * MiB);  // [D, C]
    bf16_t* bFFA   = (bf16_t*)(base + 0 * MiB);    // [M, C] bf16 (bI..bWV dead)
    float*  pF     = (float*)(base + 32 * MiB);    // 4x [M,D] fp32 FFB partials
                                                   // [32,96) MiB, dead there

    const dim3 blk(256);
    const dim3 blk512(512);

    // ---- prep: casts + weight transposes ----
    cast4_bf16<<<dim3(MD / 1024, 4), blk, 0, stream>>>(I, WQ, WK, WV, bI, MD, MD);
    transpose_to_bf16<<<dim3(D / 32, D / 32), blk, 0, stream>>>(WZ,   bWZT,   D, D);
    transpose_to_bf16<<<dim3(C / 32, D / 32), blk, 0, stream>>>(WFFA, bWFFAT, D, C);
    transpose_to_bf16<<<dim3(D / 32, C / 32), blk, 0, stream>>>(WFFB, bWFFBT, C, D);

    // ---- QKV in one z=3 dispatch; V -> bVT transposed ----
    gemm256d_bt<bf16_t><<<dim3(8, 8, 3), blk512, 0, stream>>>(
        bI, bWQ, bQ, D, D, D, D, 0, MD, MD, /*ct_z=*/2, bVT, M);

    // ---- flash attention: Q,K,VT -> AV ----
    flash_attn<<<dim3(M / 64, 16), blk, 0, stream>>>(bQ, bK, bVT, bAV, M, D);

    // ---- Z = AV x WZ^T (64 tiles at 256^2 -> keep 128^2 kernel) ----
    gemm_bt<bf16_t, false><<<dim3(16, 16, 1), blk, 0, stream>>>(
        bAV, bWZT, bZ, M, D, D, D, D, D, 0, 0, 0, -1, nullptr, 0);

    // ---- FFA = Z x WFFA^T ----
    gemm256d_bt<bf16_t><<<dim3(32, 8, 1), blk512, 0, stream>>>(
        bZ, bWFFAT, bFFA, D, D, D, C, 0, 0, 0, -1, nullptr, 0);

    // ---- FFB = FFA x WFFB^T, split-K=4 -> fp32 partials (plain stores) ----
    gemm256d_bt<float><<<dim3(8, 8, 4), blk512, 0, stream>>>(
        bFFA, bWFFBT, pF, 2048, C, C, D, 2048, 2048, MD, -1, nullptr, 0);

    // ---- out = sum of 4 partials ----
    reduce4_f32<<<dim3((int)(MD / 1024)), blk, 0, stream>>>(pF, out, MD);
}